// Round 9
// baseline (425.032 us; speedup 1.0000x reference)
//
#include <hip/hip_runtime.h>

#define N_NODES    100000
#define N_EDGES    1600000
#define IN_F       64
#define OUT_F      40
#define N_CLUSTERS 10000

#define NBLK       ((N_NODES + 255) / 256)            // 391

typedef _Float16 half_t;
typedef _Float16 half4_t __attribute__((ext_vector_type(4)));

// ---------------------------------------------------------------- R8 direct CSR build
// Replaces bin_scatter+csr_build (two-phase LDS binning, est. 55-65 us of the
// 315 us round): degree-count via L2 atomics, two-level exclusive scan,
// finalize, cursor scatter. Streaming floor ~7 us; predicted ~20-25 us total.
// Edge order within a row changes (arrival vs bucket order) — fp32
// reassociation only.
__global__ __launch_bounds__(256) void deg_kernel(
        const int* __restrict__ rows, int* __restrict__ deg) {
    int i = blockIdx.x * 256 + threadIdx.x;
    int stride = gridDim.x * 256;
    for (; i < N_EDGES; i += stride) atomicAdd(&deg[rows[i]], 1);
}

__global__ __launch_bounds__(256) void scan_local_kernel(
        const int* __restrict__ deg, int* __restrict__ exloc, int* __restrict__ bsum) {
    __shared__ int sc[256];
    int b = blockIdx.x, t = threadIdx.x;
    int i = b * 256 + t;
    int v = (i < N_NODES) ? deg[i] : 0;
    sc[t] = v;
    __syncthreads();
    for (int off = 1; off < 256; off <<= 1) {
        int a = (t >= off) ? sc[t - off] : 0;
        __syncthreads();
        sc[t] += a;
        __syncthreads();
    }
    if (i < N_NODES) exloc[i] = sc[t] - v;
    if (t == 255) bsum[b] = sc[255];
}

__global__ __launch_bounds__(512) void scan_block_kernel(
        const int* __restrict__ bsum, int* __restrict__ boff) {
    __shared__ int sc[512];
    int t = threadIdx.x;
    int v = (t < NBLK) ? bsum[t] : 0;
    sc[t] = v;
    __syncthreads();
    for (int off = 1; off < 512; off <<= 1) {
        int a = (t >= off) ? sc[t - off] : 0;
        __syncthreads();
        sc[t] += a;
        __syncthreads();
    }
    if (t < NBLK) boff[t] = sc[t] - v;
}

__global__ __launch_bounds__(256) void rowinfo_kernel(
        const int* __restrict__ deg, const int* __restrict__ exloc,
        const int* __restrict__ boff, uint2* __restrict__ rowinfo,
        float* __restrict__ dinv, const int* __restrict__ cl,
        int* __restrict__ ccnt) {
    int i = blockIdx.x * 256 + threadIdx.x;
    if (i >= N_NODES) return;
    int d = deg[i];
    int beg = exloc[i] + boff[i >> 8];
    rowinfo[i] = make_uint2((unsigned)beg, (unsigned)d);
    dinv[i] = rsqrtf((float)(d + 1));
    atomicAdd(&ccnt[cl[i]], 1);
}

__global__ __launch_bounds__(256) void scatter_kernel(
        const int* __restrict__ rows, const int* __restrict__ cols,
        const uint2* __restrict__ rowinfo, int* __restrict__ cur,
        int* __restrict__ csr_col) {
    int i = blockIdx.x * 256 + threadIdx.x;
    int stride = gridDim.x * 256;
    for (; i < N_EDGES; i += stride) {
        int r = rows[i], c = cols[i];
        int pos = atomicAdd(&cur[r], 1);
        csr_col[(int)rowinfo[r].x + pos] = c;
    }
}

// ---------------------------------------------------------------- prologue: z0 = fp16(dinv * (x @ W^T))
// R6 structure (measured: dropped out of top-5): x-row loaded ONCE into 16
// float4 registers, W broadcast from LDS (wave-uniform addresses, zero
// conflicts), half4-packed stores.
__global__ __launch_bounds__(256) void prologue_kernel(
        const float4* __restrict__ x4, const float* __restrict__ W,
        const float* __restrict__ dinv, half_t* __restrict__ z0) {
    __shared__ float Ws[OUT_F * 68];      // 40 rows x 17 float4 (16B-aligned rows)
    int t = threadIdx.x;
    for (int i = t; i < OUT_F * IN_F; i += 256)
        Ws[(i >> 6) * 68 + (i & 63)] = W[i];
    __syncthreads();
    int node = blockIdx.x * 256 + t;
    if (node >= N_NODES) return;
    float4 xr[16];
    const float4* xp = x4 + (size_t)node * 16;
    #pragma unroll
    for (int k = 0; k < 16; ++k) xr[k] = xp[k];
    float d = dinv[node];
    half4_t* zp = (half4_t*)(z0 + (size_t)node * OUT_F);
    #pragma unroll
    for (int oq = 0; oq < 10; ++oq) {
        half4_t h;
        #pragma unroll
        for (int c = 0; c < 4; ++c) {
            const float4* wr = (const float4*)(Ws + (oq * 4 + c) * 68);
            float acc = 0.f;
            #pragma unroll
            for (int k = 0; k < 16; ++k) {
                float4 wv = wr[k];
                acc += xr[k].x * wv.x + xr[k].y * wv.y
                     + xr[k].z * wv.z + xr[k].w * wv.w;
            }
            h[c] = (half_t)(acc * d);
        }
        zp[oq] = h;
    }
}

// ---------------------------------------------------------------- 40-dim fp16 pull hop, 16 nodes/block
// R4 version RESTORED verbatim (measured 76.3-76.8 us/hop, FETCH 90 MB,
// WRITE 62.5 MB FINAL). R7's A/B row split REGRESSED (FETCH 110 MB: region B
// is a SECOND line per edge -> 2.0 line-touches vs 1.5; atomic instr 4->8 per
// lane doubled WRITE to 137.5 MB -> 153 us). HW model: device-scope float
// atomics write through L2 (per-XCD L2 non-coherent); atomic WRITE traffic
// scales with instruction count; at R4's 10-lane x 4-atomic layout they hide
// under the gather (hop<0> == hop<1> == 76 us).
// Groups of 4 slot-iterations, branch-free: 4 shfls, 4 independent 8 B gathers
// (4-deep MLP/lane), masked accumulates. All trip counts wave-uniform.
template<int FINAL>
__global__ __launch_bounds__(256, 8) void hop40_kernel(
        const half_t* __restrict__ zin, half_t* __restrict__ zout,
        const uint2* __restrict__ rowinfo, const int* __restrict__ csr_col,
        const float* __restrict__ dinv, const int* __restrict__ cl,
        float* __restrict__ xc) {
    __shared__ half4_t srow[160];         // 16 rows x 10 half4 = 1280 B
    int t = threadIdx.x;
    int w = t >> 6;
    int lane = t & 63;
    int slot = lane / 10;                 // 6 => lanes 60..63 idle (masked, still shfl sources)
    int ql = lane - slot * 10;
    int slotj = (slot < 6) ? slot : 1000; // idle slots: masks always 0
    int nb = blockIdx.x << 4;
    #pragma unroll
    for (int i = 0; i < 4; ++i) {
        int node = nb + (w << 2) + i;
        uint2 ri = rowinfo[node];
        int beg = (int)ri.x;
        int end = beg + (int)ri.y;
        float4 acc = make_float4(0.f, 0.f, 0.f, 0.f);
        if (slot == 0) {                  // self-loop
            half4_t v = ((const half4_t*)(zin + (size_t)node * OUT_F))[ql];
            acc.x = (float)v.x; acc.y = (float)v.y; acc.z = (float)v.z; acc.w = (float)v.w;
        }
        for (int base = beg; base < end; base += 64) {
            int idx = base + lane;
            int cv = (idx < end) ? csr_col[idx] : 0;
            int lim = min(64, end - base);        // wave-uniform (>=1 here)
            int gmax = (lim + 23) / 24;           // wave-uniform; groups of 4 slot-iters
            for (int g = 0; g < gmax; ++g) {
                int j0 = g * 24 + slotj;
                int c0 = __shfl(cv, (j0     ) & 63);
                int c1 = __shfl(cv, (j0 +  6) & 63);
                int c2 = __shfl(cv, (j0 + 12) & 63);
                int c3 = __shfl(cv, (j0 + 18) & 63);
                half4_t v0 = ((const half4_t*)(zin + (size_t)c0 * OUT_F))[ql];
                half4_t v1 = ((const half4_t*)(zin + (size_t)c1 * OUT_F))[ql];
                half4_t v2 = ((const half4_t*)(zin + (size_t)c2 * OUT_F))[ql];
                half4_t v3 = ((const half4_t*)(zin + (size_t)c3 * OUT_F))[ql];
                float m0 = (j0      < lim) ? 1.f : 0.f;
                float m1 = (j0 +  6 < lim) ? 1.f : 0.f;
                float m2 = (j0 + 12 < lim) ? 1.f : 0.f;
                float m3 = (j0 + 18 < lim) ? 1.f : 0.f;
                acc.x += m0 * (float)v0.x; acc.y += m0 * (float)v0.y;
                acc.z += m0 * (float)v0.z; acc.w += m0 * (float)v0.w;
                acc.x += m1 * (float)v1.x; acc.y += m1 * (float)v1.y;
                acc.z += m1 * (float)v1.z; acc.w += m1 * (float)v1.w;
                acc.x += m2 * (float)v2.x; acc.y += m2 * (float)v2.y;
                acc.z += m2 * (float)v2.z; acc.w += m2 * (float)v2.w;
                acc.x += m3 * (float)v3.x; acc.y += m3 * (float)v3.y;
                acc.z += m3 * (float)v3.z; acc.w += m3 * (float)v3.w;
            }
        }
        // reduce 6 slots: fold +30, then +10 and +20
        float4 t1;
        t1.x = __shfl(acc.x, (lane + 30) & 63); t1.y = __shfl(acc.y, (lane + 30) & 63);
        t1.z = __shfl(acc.z, (lane + 30) & 63); t1.w = __shfl(acc.w, (lane + 30) & 63);
        if (lane < 30) { acc.x += t1.x; acc.y += t1.y; acc.z += t1.z; acc.w += t1.w; }
        float4 t2, t3;
        t2.x = __shfl(acc.x, (lane + 10) & 63); t2.y = __shfl(acc.y, (lane + 10) & 63);
        t2.z = __shfl(acc.z, (lane + 10) & 63); t2.w = __shfl(acc.w, (lane + 10) & 63);
        t3.x = __shfl(acc.x, (lane + 20) & 63); t3.y = __shfl(acc.y, (lane + 20) & 63);
        t3.z = __shfl(acc.z, (lane + 20) & 63); t3.w = __shfl(acc.w, (lane + 20) & 63);
        if (lane < 10) {
            acc.x += t2.x + t3.x; acc.y += t2.y + t3.y;
            acc.z += t2.z + t3.z; acc.w += t2.w + t3.w;
            float d = dinv[node];
            if (FINAL) {
                float* p = xc + cl[node] * OUT_F + ql * 4;
                atomicAdd(p + 0, acc.x * d); atomicAdd(p + 1, acc.y * d);
                atomicAdd(p + 2, acc.z * d); atomicAdd(p + 3, acc.w * d);
            } else {
                float s = d * d;
                half4_t o;
                o.x = (half_t)(acc.x * s); o.y = (half_t)(acc.y * s);
                o.z = (half_t)(acc.z * s); o.w = (half_t)(acc.w * s);
                srow[((w << 2) + i) * 10 + ql] = o;
            }
        }
    }
    if (!FINAL) {
        __syncthreads();
        if (t < 160) ((half4_t*)zout)[(size_t)blockIdx.x * 160 + t] = srow[t];
    }
}

// ---------------------------------------------------------------- epilogue: out[n] = xc[cl[n]]/cnt + b
__global__ void epilogue_kernel(const float4* __restrict__ xc4, const int* __restrict__ ccnt,
                                const float4* __restrict__ b4, const int* __restrict__ cl,
                                float4* __restrict__ out4) {
    int i = blockIdx.x * 256 + threadIdx.x;
    if (i >= N_NODES * (OUT_F / 4)) return;
    int node = i / 10;
    int q = i - node * 10;
    int c = cl[node];
    float inv = 1.0f / fmaxf((float)ccnt[c], 1.0f);
    float4 v = xc4[c * 10 + q];
    float4 bb = b4[q];
    v.x = v.x * inv + bb.x; v.y = v.y * inv + bb.y;
    v.z = v.z * inv + bb.z; v.w = v.w * inv + bb.w;
    out4[i] = v;
}

// ---------------------------------------------------------------- launch
extern "C" void kernel_launch(void* const* d_in, const int* in_sizes, int n_in,
                              void* d_out, int out_size, void* d_ws, size_t ws_size,
                              hipStream_t stream) {
    const float* x    = (const float*)d_in[0];
    const int*   rows = (const int*)d_in[1];
    const int*   cols = (const int*)d_in[1] + N_EDGES;
    const int*   cl   = (const int*)d_in[2];
    const float* W    = (const float*)d_in[4];
    const float* b    = (const float*)d_in[5];
    float* out = (float*)d_out;

    size_t off = 0;
    auto alloc = [&](size_t elems) -> void* {          // 256 B aligned
        void* p = (char*)d_ws + off * 4;
        off += (elems + 63) & ~(size_t)63;
        return p;
    };
    // zeroed region first (single memset): ccnt | xc_sum | deg | cur
    int*   ccnt    = (int*)alloc(N_CLUSTERS);
    float* xc_sum  = (float*)alloc((size_t)N_CLUSTERS * OUT_F);
    int*   deg     = (int*)alloc(N_NODES);
    int*   cur     = (int*)alloc(N_NODES);
    size_t zero_elems = off;
    float* dinv      = (float*)alloc(N_NODES);
    uint2* rowinfo   = (uint2*)alloc((size_t)N_NODES * 2);
    int*   csr_col   = (int*)alloc((size_t)N_EDGES);                 // 6.4 MB
    int*   exloc     = (int*)alloc(N_NODES);
    int*   bsum      = (int*)alloc(512);
    int*   boff      = (int*)alloc(512);
    half_t* bufA     = (half_t*)alloc((size_t)N_NODES * OUT_F / 2);  // 8 MB fp16
    half_t* bufB     = (half_t*)alloc((size_t)N_NODES * OUT_F / 2);  // 8 MB fp16
    (void)ws_size; (void)in_sizes; (void)n_in; (void)out_size;

    hipMemsetAsync(d_ws, 0, zero_elems * 4, stream);

    const int HB = N_NODES / 16;                      // 6250

    deg_kernel<<<2048, 256, 0, stream>>>(rows, deg);
    scan_local_kernel<<<NBLK, 256, 0, stream>>>(deg, exloc, bsum);
    scan_block_kernel<<<1, 512, 0, stream>>>(bsum, boff);
    rowinfo_kernel<<<NBLK, 256, 0, stream>>>(deg, exloc, boff, rowinfo, dinv, cl, ccnt);
    scatter_kernel<<<2048, 256, 0, stream>>>(rows, cols, rowinfo, cur, csr_col);

    prologue_kernel<<<(N_NODES + 255) / 256, 256, 0, stream>>>(
        (const float4*)x, W, dinv, bufA);

    hop40_kernel<0><<<HB, 256, 0, stream>>>(bufA, bufB, rowinfo, csr_col, dinv, cl, xc_sum);
    hop40_kernel<0><<<HB, 256, 0, stream>>>(bufB, bufA, rowinfo, csr_col, dinv, cl, xc_sum);
    hop40_kernel<1><<<HB, 256, 0, stream>>>(bufA, (half_t*)nullptr, rowinfo, csr_col, dinv, cl, xc_sum);

    epilogue_kernel<<<(N_NODES * (OUT_F / 4) + 255) / 256, 256, 0, stream>>>(
        (const float4*)xc_sum, ccnt, (const float4*)b, cl, (float4*)out);
}

// Round 10
// 325.149 us; speedup vs baseline: 1.3072x; 1.3072x over previous
//
#include <hip/hip_runtime.h>

#define N_NODES    100000
#define N_EDGES    1600000
#define IN_F       64
#define OUT_F      40
#define N_CLUSTERS 10000

#define BUCK_SHIFT 7                                  // 128 rows per bucket
#define BROWS      128
#define NBUCK      ((N_NODES + BROWS - 1) >> BUCK_SHIFT)   // 782
#define CAP        2560                               // mean 2048, sigma 45 -> +11 sigma
#define TILE_E     4096
#define EPT        (TILE_E / 256)                     // 16 edges per thread

typedef _Float16 half_t;
typedef _Float16 half4_t __attribute__((ext_vector_type(4)));

// ---------------------------------------------------------------- bin scatter (single edge pass)
// RESTORED (R8 lesson): the two-phase LDS binning makes csr writes bucket-
// local. R8's "lean" direct scatter did random 4 B writes across 6.4 MB ->
// 107 MB WRITE (full line per write) and 100 us alone. This structure IS the
// optimization.
__global__ __launch_bounds__(256) void bin_scatter_kernel(
        const int* __restrict__ rows, const int* __restrict__ cols,
        int* __restrict__ bcursor, unsigned* __restrict__ bins) {
    __shared__ uint2 se[TILE_E];          // 32 KB, ordered by bucket
    __shared__ int lh[NBUCK];
    __shared__ int lsc[NBUCK];
    __shared__ int lb[NBUCK];
    __shared__ int sc[256];
    int t = threadIdx.x;
    for (int i = t; i < NBUCK; i += 256) lh[i] = 0;
    __syncthreads();
    int e0 = blockIdx.x * TILE_E;
    int r[EPT], c[EPT], rk[EPT];
    #pragma unroll
    for (int k = 0; k < EPT; ++k) {
        int e = e0 + t + k * 256;
        if (e < N_EDGES) {
            r[k] = rows[e]; c[k] = cols[e];
            rk[k] = atomicAdd(&lh[r[k] >> BUCK_SHIFT], 1);
        } else r[k] = -1;
    }
    __syncthreads();
    int b4 = t * 4;
    int a0 = (b4 + 0 < NBUCK) ? lh[b4 + 0] : 0;
    int a1 = (b4 + 1 < NBUCK) ? lh[b4 + 1] : 0;
    int a2 = (b4 + 2 < NBUCK) ? lh[b4 + 2] : 0;
    int a3 = (b4 + 3 < NBUCK) ? lh[b4 + 3] : 0;
    int thr = a0 + a1 + a2 + a3;
    sc[t] = thr;
    __syncthreads();
    for (int off = 1; off < 256; off <<= 1) {
        int a = (t >= off) ? sc[t - off] : 0;
        __syncthreads();
        sc[t] += a;
        __syncthreads();
    }
    int ex = sc[t] - thr;
    if (b4 + 0 < NBUCK) { lsc[b4 + 0] = ex;                lb[b4 + 0] = a0 ? atomicAdd(&bcursor[b4 + 0], a0) : 0; }
    if (b4 + 1 < NBUCK) { lsc[b4 + 1] = ex + a0;           lb[b4 + 1] = a1 ? atomicAdd(&bcursor[b4 + 1], a1) : 0; }
    if (b4 + 2 < NBUCK) { lsc[b4 + 2] = ex + a0 + a1;      lb[b4 + 2] = a2 ? atomicAdd(&bcursor[b4 + 2], a2) : 0; }
    if (b4 + 3 < NBUCK) { lsc[b4 + 3] = ex + a0 + a1 + a2; lb[b4 + 3] = a3 ? atomicAdd(&bcursor[b4 + 3], a3) : 0; }
    __syncthreads();
    #pragma unroll
    for (int k = 0; k < EPT; ++k) {
        if (r[k] >= 0) {
            int bu = r[k] >> BUCK_SHIFT;
            se[lsc[bu] + rk[k]] = make_uint2((unsigned)r[k], (unsigned)c[k]);
        }
    }
    __syncthreads();
    #pragma unroll
    for (int k = 0; k < EPT; ++k) {
        int idx = k * 256 + t;
        if (e0 + idx < N_EDGES) {
            uint2 u = se[idx];
            int bu = (int)(u.x >> BUCK_SHIFT);
            int pos = lb[bu] + (idx - lsc[bu]);
            if (pos < CAP)
                bins[(size_t)bu * CAP + pos] = ((u.x & (BROWS - 1)) << 17) | u.y;
        }
    }
}

// ---------------------------------------------------------------- CSR build per bucket
__global__ __launch_bounds__(256) void csr_build_kernel(
        const unsigned* __restrict__ bins, const int* __restrict__ bcnt,
        int* __restrict__ csr_col, uint2* __restrict__ rowinfo,
        float* __restrict__ dinv, const int* __restrict__ cl,
        int* __restrict__ ccnt) {
    __shared__ int lcnt[BROWS];
    __shared__ int gbeg[BROWS];
    __shared__ int sc[BROWS];
    int b = blockIdx.x, t = threadIdx.x;
    int n = min(bcnt[b], CAP);
    const unsigned* eb = bins + (size_t)b * CAP;
    if (t < BROWS) lcnt[t] = 0;
    __syncthreads();
    for (int i = t; i < n; i += 256) atomicAdd(&lcnt[eb[i] >> 17], 1);
    __syncthreads();
    int v = (t < BROWS) ? lcnt[t] : 0;
    if (t < BROWS) sc[t] = v;
    __syncthreads();
    for (int off = 1; off < BROWS; off <<= 1) {
        int a = (t >= off && t < BROWS) ? sc[t - off] : 0;
        __syncthreads();
        if (t < BROWS) sc[t] += a;
        __syncthreads();
    }
    if (t < BROWS) {
        int beg = b * CAP + sc[t] - v;
        gbeg[t] = beg;
        int grow = (b << BUCK_SHIFT) + t;
        if (grow < N_NODES) {
            rowinfo[grow] = make_uint2((unsigned)beg, (unsigned)v);
            dinv[grow] = rsqrtf((float)(v + 1));
            atomicAdd(&ccnt[cl[grow]], 1);
        }
        lcnt[t] = 0;        // reuse as per-row cursor
    }
    __syncthreads();
    for (int i = t; i < n; i += 256) {
        unsigned u = eb[i];
        int lrow = (int)(u >> 17);
        int pos = atomicAdd(&lcnt[lrow], 1);
        csr_col[gbeg[lrow] + pos] = (int)(u & 0x1FFFFu);
    }
}

// ---------------------------------------------------------------- prologue: z0 = fp16(dinv * (x @ W^T))
// R6 structure (measured win: dropped out of top-5, ~70 -> ~28 us): x-row
// loaded ONCE into 16 float4 registers, W broadcast from LDS (wave-uniform
// addresses, zero conflicts), half4-packed stores. Known remaining headroom:
// grid-limited to ~6 waves/CU (100K threads / 256 CU), floor ~5 us.
__global__ __launch_bounds__(256) void prologue_kernel(
        const float4* __restrict__ x4, const float* __restrict__ W,
        const float* __restrict__ dinv, half_t* __restrict__ z0) {
    __shared__ float Ws[OUT_F * 68];      // 40 rows x 17 float4 (16B-aligned rows)
    int t = threadIdx.x;
    for (int i = t; i < OUT_F * IN_F; i += 256)
        Ws[(i >> 6) * 68 + (i & 63)] = W[i];
    __syncthreads();
    int node = blockIdx.x * 256 + t;
    if (node >= N_NODES) return;
    float4 xr[16];
    const float4* xp = x4 + (size_t)node * 16;
    #pragma unroll
    for (int k = 0; k < 16; ++k) xr[k] = xp[k];
    float d = dinv[node];
    half4_t* zp = (half4_t*)(z0 + (size_t)node * OUT_F);
    #pragma unroll
    for (int oq = 0; oq < 10; ++oq) {
        half4_t h;
        #pragma unroll
        for (int c = 0; c < 4; ++c) {
            const float4* wr = (const float4*)(Ws + (oq * 4 + c) * 68);
            float acc = 0.f;
            #pragma unroll
            for (int k = 0; k < 16; ++k) {
                float4 wv = wr[k];
                acc += xr[k].x * wv.x + xr[k].y * wv.y
                     + xr[k].z * wv.z + xr[k].w * wv.w;
            }
            h[c] = (half_t)(acc * d);
        }
        zp[oq] = h;
    }
}

// ---------------------------------------------------------------- 40-dim fp16 pull hop, 16 nodes/block
// R4 version (measured 76.3-76.8 us/hop, FETCH 90 MB, WRITE 62.5 MB).
// R9 tweak: csr_col loads are NONTEMPORAL — the 6.4 MB index stream is read
// once per hop; nt keeps it from evicting the 8 MB z gather set in L2.
// Measured model: dur tracks hbm_bytes at ~2 TB/s (random-line service rate);
// R4's 4x MLP only gave -5% => service-rate bound, so bytes are the lever.
// Groups of 4 slot-iterations, branch-free: 4 shfls, 4 independent 8 B gathers
// (4-deep MLP/lane), masked accumulates. All trip counts wave-uniform (from
// rowinfo[node], node uniform per wave) => every lane reaches every __shfl
// with all 64 sources active (R8/R9 prior-session hazard structurally excluded).
template<int FINAL>
__global__ __launch_bounds__(256, 8) void hop40_kernel(
        const half_t* __restrict__ zin, half_t* __restrict__ zout,
        const uint2* __restrict__ rowinfo, const int* __restrict__ csr_col,
        const float* __restrict__ dinv, const int* __restrict__ cl,
        float* __restrict__ xc) {
    __shared__ half4_t srow[160];         // 16 rows x 10 half4 = 1280 B
    int t = threadIdx.x;
    int w = t >> 6;
    int lane = t & 63;
    int slot = lane / 10;                 // 6 => lanes 60..63 idle (masked, still shfl sources)
    int ql = lane - slot * 10;
    int slotj = (slot < 6) ? slot : 1000; // idle slots: masks always 0
    int nb = blockIdx.x << 4;
    #pragma unroll
    for (int i = 0; i < 4; ++i) {
        int node = nb + (w << 2) + i;
        uint2 ri = rowinfo[node];
        int beg = (int)ri.x;
        int end = beg + (int)ri.y;
        float4 acc = make_float4(0.f, 0.f, 0.f, 0.f);
        if (slot == 0) {                  // self-loop
            half4_t v = ((const half4_t*)(zin + (size_t)node * OUT_F))[ql];
            acc.x = (float)v.x; acc.y = (float)v.y; acc.z = (float)v.z; acc.w = (float)v.w;
        }
        for (int base = beg; base < end; base += 64) {
            int idx = base + lane;
            int cv = (idx < end) ? __builtin_nontemporal_load(csr_col + idx) : 0;
            int lim = min(64, end - base);        // wave-uniform (>=1 here)
            int gmax = (lim + 23) / 24;           // wave-uniform; groups of 4 slot-iters
            for (int g = 0; g < gmax; ++g) {
                int j0 = g * 24 + slotj;
                int c0 = __shfl(cv, (j0     ) & 63);
                int c1 = __shfl(cv, (j0 +  6) & 63);
                int c2 = __shfl(cv, (j0 + 12) & 63);
                int c3 = __shfl(cv, (j0 + 18) & 63);
                half4_t v0 = ((const half4_t*)(zin + (size_t)c0 * OUT_F))[ql];
                half4_t v1 = ((const half4_t*)(zin + (size_t)c1 * OUT_F))[ql];
                half4_t v2 = ((const half4_t*)(zin + (size_t)c2 * OUT_F))[ql];
                half4_t v3 = ((const half4_t*)(zin + (size_t)c3 * OUT_F))[ql];
                float m0 = (j0      < lim) ? 1.f : 0.f;
                float m1 = (j0 +  6 < lim) ? 1.f : 0.f;
                float m2 = (j0 + 12 < lim) ? 1.f : 0.f;
                float m3 = (j0 + 18 < lim) ? 1.f : 0.f;
                acc.x += m0 * (float)v0.x; acc.y += m0 * (float)v0.y;
                acc.z += m0 * (float)v0.z; acc.w += m0 * (float)v0.w;
                acc.x += m1 * (float)v1.x; acc.y += m1 * (float)v1.y;
                acc.z += m1 * (float)v1.z; acc.w += m1 * (float)v1.w;
                acc.x += m2 * (float)v2.x; acc.y += m2 * (float)v2.y;
                acc.z += m2 * (float)v2.z; acc.w += m2 * (float)v2.w;
                acc.x += m3 * (float)v3.x; acc.y += m3 * (float)v3.y;
                acc.z += m3 * (float)v3.z; acc.w += m3 * (float)v3.w;
            }
        }
        // reduce 6 slots: fold +30, then +10 and +20
        float4 t1;
        t1.x = __shfl(acc.x, (lane + 30) & 63); t1.y = __shfl(acc.y, (lane + 30) & 63);
        t1.z = __shfl(acc.z, (lane + 30) & 63); t1.w = __shfl(acc.w, (lane + 30) & 63);
        if (lane < 30) { acc.x += t1.x; acc.y += t1.y; acc.z += t1.z; acc.w += t1.w; }
        float4 t2, t3;
        t2.x = __shfl(acc.x, (lane + 10) & 63); t2.y = __shfl(acc.y, (lane + 10) & 63);
        t2.z = __shfl(acc.z, (lane + 10) & 63); t2.w = __shfl(acc.w, (lane + 10) & 63);
        t3.x = __shfl(acc.x, (lane + 20) & 63); t3.y = __shfl(acc.y, (lane + 20) & 63);
        t3.z = __shfl(acc.z, (lane + 20) & 63); t3.w = __shfl(acc.w, (lane + 20) & 63);
        if (lane < 10) {
            acc.x += t2.x + t3.x; acc.y += t2.y + t3.y;
            acc.z += t2.z + t3.z; acc.w += t2.w + t3.w;
            float d = dinv[node];
            if (FINAL) {
                float* p = xc + cl[node] * OUT_F + ql * 4;
                atomicAdd(p + 0, acc.x * d); atomicAdd(p + 1, acc.y * d);
                atomicAdd(p + 2, acc.z * d); atomicAdd(p + 3, acc.w * d);
            } else {
                float s = d * d;
                half4_t o;
                o.x = (half_t)(acc.x * s); o.y = (half_t)(acc.y * s);
                o.z = (half_t)(acc.z * s); o.w = (half_t)(acc.w * s);
                srow[((w << 2) + i) * 10 + ql] = o;
            }
        }
    }
    if (!FINAL) {
        __syncthreads();
        if (t < 160) ((half4_t*)zout)[(size_t)blockIdx.x * 160 + t] = srow[t];
    }
}

// ---------------------------------------------------------------- epilogue: out[n] = xc[cl[n]]/cnt + b
__global__ void epilogue_kernel(const float4* __restrict__ xc4, const int* __restrict__ ccnt,
                                const float4* __restrict__ b4, const int* __restrict__ cl,
                                float4* __restrict__ out4) {
    int i = blockIdx.x * 256 + threadIdx.x;
    if (i >= N_NODES * (OUT_F / 4)) return;
    int node = i / 10;
    int q = i - node * 10;
    int c = cl[node];
    float inv = 1.0f / fmaxf((float)ccnt[c], 1.0f);
    float4 v = xc4[c * 10 + q];
    float4 bb = b4[q];
    v.x = v.x * inv + bb.x; v.y = v.y * inv + bb.y;
    v.z = v.z * inv + bb.z; v.w = v.w * inv + bb.w;
    out4[i] = v;
}

// ---------------------------------------------------------------- launch
extern "C" void kernel_launch(void* const* d_in, const int* in_sizes, int n_in,
                              void* d_out, int out_size, void* d_ws, size_t ws_size,
                              hipStream_t stream) {
    const float* x    = (const float*)d_in[0];
    const int*   rows = (const int*)d_in[1];
    const int*   cols = (const int*)d_in[1] + N_EDGES;
    const int*   cl   = (const int*)d_in[2];
    const float* W    = (const float*)d_in[4];
    const float* b    = (const float*)d_in[5];
    float* out = (float*)d_out;

    size_t off = 0;
    auto alloc = [&](size_t elems) -> void* {          // 256 B aligned
        void* p = (char*)d_ws + off * 4;
        off += (elems + 63) & ~(size_t)63;
        return p;
    };
    // zeroed region first (single memset): ccnt | xc_sum | bcursor
    int*   ccnt    = (int*)alloc(N_CLUSTERS);
    float* xc_sum  = (float*)alloc((size_t)N_CLUSTERS * OUT_F);
    int*   bcursor = (int*)alloc(NBUCK);
    size_t zero_elems = off;
    float* dinv      = (float*)alloc(N_NODES);
    uint2* rowinfo   = (uint2*)alloc((size_t)N_NODES * 2);
    int*   csr_col   = (int*)alloc((size_t)NBUCK * CAP);             // 8 MB
    unsigned* bins   = (unsigned*)alloc((size_t)NBUCK * CAP);        // 8 MB
    half_t* bufA     = (half_t*)alloc((size_t)N_NODES * OUT_F / 2);  // 8 MB fp16
    half_t* bufB     = (half_t*)alloc((size_t)N_NODES * OUT_F / 2);  // 8 MB fp16
    (void)ws_size; (void)in_sizes; (void)n_in; (void)out_size;

    hipMemsetAsync(d_ws, 0, zero_elems * 4, stream);

    const int TB = (N_EDGES + TILE_E - 1) / TILE_E;   // 391
    const int HB = N_NODES / 16;                      // 6250

    bin_scatter_kernel<<<TB, 256, 0, stream>>>(rows, cols, bcursor, bins);
    csr_build_kernel<<<NBUCK, 256, 0, stream>>>(bins, bcursor, csr_col, rowinfo,
                                                dinv, cl, ccnt);

    prologue_kernel<<<(N_NODES + 255) / 256, 256, 0, stream>>>(
        (const float4*)x, W, dinv, bufA);

    hop40_kernel<0><<<HB, 256, 0, stream>>>(bufA, bufB, rowinfo, csr_col, dinv, cl, xc_sum);
    hop40_kernel<0><<<HB, 256, 0, stream>>>(bufB, bufA, rowinfo, csr_col, dinv, cl, xc_sum);
    hop40_kernel<1><<<HB, 256, 0, stream>>>(bufA, (half_t*)nullptr, rowinfo, csr_col, dinv, cl, xc_sum);

    epilogue_kernel<<<(N_NODES * (OUT_F / 4) + 255) / 256, 256, 0, stream>>>(
        (const float4*)xc_sum, ccnt, (const float4*)b, cl, (float4*)out);
}

// Round 11
// 319.073 us; speedup vs baseline: 1.3321x; 1.0190x over previous
//
#include <hip/hip_runtime.h>

#define N_NODES    100000
#define N_EDGES    1600000
#define IN_F       64
#define OUT_F      40
#define N_CLUSTERS 10000

#define BUCK_SHIFT 7                                  // 128 rows per bucket
#define BROWS      128
#define NBUCK      ((N_NODES + BROWS - 1) >> BUCK_SHIFT)   // 782
#define CAP        2560                               // mean 2048, sigma 45 -> +11 sigma
#define TILE_E     4096
#define EPT        (TILE_E / 256)                     // 16 edges per thread

typedef _Float16 half_t;
typedef _Float16 half4_t __attribute__((ext_vector_type(4)));

// ---------------------------------------------------------------- bin scatter (single edge pass)
// KEEP (R8 lesson): the two-phase LDS binning makes csr writes bucket-local.
// R8's direct scatter did random 4 B writes across 6.4 MB -> 107 MB WRITE
// (full line per write), 100 us alone. This structure IS the optimization.
__global__ __launch_bounds__(256) void bin_scatter_kernel(
        const int* __restrict__ rows, const int* __restrict__ cols,
        int* __restrict__ bcursor, unsigned* __restrict__ bins) {
    __shared__ uint2 se[TILE_E];          // 32 KB, ordered by bucket
    __shared__ int lh[NBUCK];
    __shared__ int lsc[NBUCK];
    __shared__ int lb[NBUCK];
    __shared__ int sc[256];
    int t = threadIdx.x;
    for (int i = t; i < NBUCK; i += 256) lh[i] = 0;
    __syncthreads();
    int e0 = blockIdx.x * TILE_E;
    int r[EPT], c[EPT], rk[EPT];
    #pragma unroll
    for (int k = 0; k < EPT; ++k) {
        int e = e0 + t + k * 256;
        if (e < N_EDGES) {
            r[k] = rows[e]; c[k] = cols[e];
            rk[k] = atomicAdd(&lh[r[k] >> BUCK_SHIFT], 1);
        } else r[k] = -1;
    }
    __syncthreads();
    int b4 = t * 4;
    int a0 = (b4 + 0 < NBUCK) ? lh[b4 + 0] : 0;
    int a1 = (b4 + 1 < NBUCK) ? lh[b4 + 1] : 0;
    int a2 = (b4 + 2 < NBUCK) ? lh[b4 + 2] : 0;
    int a3 = (b4 + 3 < NBUCK) ? lh[b4 + 3] : 0;
    int thr = a0 + a1 + a2 + a3;
    sc[t] = thr;
    __syncthreads();
    for (int off = 1; off < 256; off <<= 1) {
        int a = (t >= off) ? sc[t - off] : 0;
        __syncthreads();
        sc[t] += a;
        __syncthreads();
    }
    int ex = sc[t] - thr;
    if (b4 + 0 < NBUCK) { lsc[b4 + 0] = ex;                lb[b4 + 0] = a0 ? atomicAdd(&bcursor[b4 + 0], a0) : 0; }
    if (b4 + 1 < NBUCK) { lsc[b4 + 1] = ex + a0;           lb[b4 + 1] = a1 ? atomicAdd(&bcursor[b4 + 1], a1) : 0; }
    if (b4 + 2 < NBUCK) { lsc[b4 + 2] = ex + a0 + a1;      lb[b4 + 2] = a2 ? atomicAdd(&bcursor[b4 + 2], a2) : 0; }
    if (b4 + 3 < NBUCK) { lsc[b4 + 3] = ex + a0 + a1 + a2; lb[b4 + 3] = a3 ? atomicAdd(&bcursor[b4 + 3], a3) : 0; }
    __syncthreads();
    #pragma unroll
    for (int k = 0; k < EPT; ++k) {
        if (r[k] >= 0) {
            int bu = r[k] >> BUCK_SHIFT;
            se[lsc[bu] + rk[k]] = make_uint2((unsigned)r[k], (unsigned)c[k]);
        }
    }
    __syncthreads();
    #pragma unroll
    for (int k = 0; k < EPT; ++k) {
        int idx = k * 256 + t;
        if (e0 + idx < N_EDGES) {
            uint2 u = se[idx];
            int bu = (int)(u.x >> BUCK_SHIFT);
            int pos = lb[bu] + (idx - lsc[bu]);
            if (pos < CAP)
                bins[(size_t)bu * CAP + pos] = ((u.x & (BROWS - 1)) << 17) | u.y;
        }
    }
}

// ---------------------------------------------------------------- CSR build per bucket
__global__ __launch_bounds__(256) void csr_build_kernel(
        const unsigned* __restrict__ bins, const int* __restrict__ bcnt,
        int* __restrict__ csr_col, uint2* __restrict__ rowinfo,
        float* __restrict__ dinv, const int* __restrict__ cl,
        int* __restrict__ ccnt) {
    __shared__ int lcnt[BROWS];
    __shared__ int gbeg[BROWS];
    __shared__ int sc[BROWS];
    int b = blockIdx.x, t = threadIdx.x;
    int n = min(bcnt[b], CAP);
    const unsigned* eb = bins + (size_t)b * CAP;
    if (t < BROWS) lcnt[t] = 0;
    __syncthreads();
    for (int i = t; i < n; i += 256) atomicAdd(&lcnt[eb[i] >> 17], 1);
    __syncthreads();
    int v = (t < BROWS) ? lcnt[t] : 0;
    if (t < BROWS) sc[t] = v;
    __syncthreads();
    for (int off = 1; off < BROWS; off <<= 1) {
        int a = (t >= off && t < BROWS) ? sc[t - off] : 0;
        __syncthreads();
        if (t < BROWS) sc[t] += a;
        __syncthreads();
    }
    if (t < BROWS) {
        int beg = b * CAP + sc[t] - v;
        gbeg[t] = beg;
        int grow = (b << BUCK_SHIFT) + t;
        if (grow < N_NODES) {
            rowinfo[grow] = make_uint2((unsigned)beg, (unsigned)v);
            dinv[grow] = rsqrtf((float)(v + 1));
            atomicAdd(&ccnt[cl[grow]], 1);
        }
        lcnt[t] = 0;        // reuse as per-row cursor
    }
    __syncthreads();
    for (int i = t; i < n; i += 256) {
        unsigned u = eb[i];
        int lrow = (int)(u >> 17);
        int pos = atomicAdd(&lcnt[lrow], 1);
        csr_col[gbeg[lrow] + pos] = (int)(u & 0x1FFFFu);
    }
}

// ---------------------------------------------------------------- prologue: z0 = fp16(dinv * (x @ W^T))
// R10: 2 threads/node (each 20 outputs). The 100K-thread 1-thread/node version
// was grid-starved at 6.1 waves/CU and latency-bound (~28 us vs ~5 us floor):
// 16 HBM loads/thread with nothing to hide under. 200K threads -> 12 waves/CU.
// Thread pair shares the x-row; same-address loads within a wave are served
// as a broadcast, so global traffic stays ~1x. Same dots, same order -> absmax
// bit-identical. W broadcast from LDS (wave-uniform addresses, 0 conflicts).
__global__ __launch_bounds__(256) void prologue_kernel(
        const float4* __restrict__ x4, const float* __restrict__ W,
        const float* __restrict__ dinv, half_t* __restrict__ z0) {
    __shared__ float Ws[OUT_F * 68];      // 40 rows x 17 float4 (16B-aligned rows)
    int t = threadIdx.x;
    for (int i = t; i < OUT_F * IN_F; i += 256)
        Ws[(i >> 6) * 68 + (i & 63)] = W[i];
    __syncthreads();
    int idx = blockIdx.x * 256 + t;
    int node = idx >> 1;
    int hf   = idx & 1;                   // 0: outputs 0..19, 1: outputs 20..39
    if (node >= N_NODES) return;
    float4 xr[16];
    const float4* xp = x4 + (size_t)node * 16;
    #pragma unroll
    for (int k = 0; k < 16; ++k) xr[k] = xp[k];
    float d = dinv[node];
    half4_t* zp = (half4_t*)(z0 + (size_t)node * OUT_F + hf * 20);  // 40 B offset, 8B-aligned
    #pragma unroll
    for (int oq = 0; oq < 5; ++oq) {
        half4_t h;
        #pragma unroll
        for (int c = 0; c < 4; ++c) {
            const float4* wr = (const float4*)(Ws + (hf * 20 + oq * 4 + c) * 68);
            float acc = 0.f;
            #pragma unroll
            for (int k = 0; k < 16; ++k) {
                float4 wv = wr[k];
                acc += xr[k].x * wv.x + xr[k].y * wv.y
                     + xr[k].z * wv.z + xr[k].w * wv.w;
            }
            h[c] = (half_t)(acc * d);
        }
        zp[oq] = h;
    }
}

// ---------------------------------------------------------------- 40-dim fp16 pull hop, 16 nodes/block
// R4 version verbatim (measured 76.3-76.8 us/hop, FETCH 90 MB, WRITE 62.5 MB).
// R9's nontemporal csr load was NEUTRAL (FETCH unchanged) — removed.
// Measured model: dur tracks hbm_bytes at ~2 TB/s (random-line service rate);
// 4x MLP gave only -5% (R4), dim-split (R5) and row-split (R7) both regressed.
// Groups of 4 slot-iterations, branch-free: 4 shfls, 4 independent 8 B gathers
// (4-deep MLP/lane), masked accumulates. All trip counts wave-uniform (from
// rowinfo[node], node uniform per wave) => every lane reaches every __shfl
// with all 64 sources active.
template<int FINAL>
__global__ __launch_bounds__(256, 8) void hop40_kernel(
        const half_t* __restrict__ zin, half_t* __restrict__ zout,
        const uint2* __restrict__ rowinfo, const int* __restrict__ csr_col,
        const float* __restrict__ dinv, const int* __restrict__ cl,
        float* __restrict__ xc) {
    __shared__ half4_t srow[160];         // 16 rows x 10 half4 = 1280 B
    int t = threadIdx.x;
    int w = t >> 6;
    int lane = t & 63;
    int slot = lane / 10;                 // 6 => lanes 60..63 idle (masked, still shfl sources)
    int ql = lane - slot * 10;
    int slotj = (slot < 6) ? slot : 1000; // idle slots: masks always 0
    int nb = blockIdx.x << 4;
    #pragma unroll
    for (int i = 0; i < 4; ++i) {
        int node = nb + (w << 2) + i;
        uint2 ri = rowinfo[node];
        int beg = (int)ri.x;
        int end = beg + (int)ri.y;
        float4 acc = make_float4(0.f, 0.f, 0.f, 0.f);
        if (slot == 0) {                  // self-loop
            half4_t v = ((const half4_t*)(zin + (size_t)node * OUT_F))[ql];
            acc.x = (float)v.x; acc.y = (float)v.y; acc.z = (float)v.z; acc.w = (float)v.w;
        }
        for (int base = beg; base < end; base += 64) {
            int idx = base + lane;
            int cv = (idx < end) ? csr_col[idx] : 0;
            int lim = min(64, end - base);        // wave-uniform (>=1 here)
            int gmax = (lim + 23) / 24;           // wave-uniform; groups of 4 slot-iters
            for (int g = 0; g < gmax; ++g) {
                int j0 = g * 24 + slotj;
                int c0 = __shfl(cv, (j0     ) & 63);
                int c1 = __shfl(cv, (j0 +  6) & 63);
                int c2 = __shfl(cv, (j0 + 12) & 63);
                int c3 = __shfl(cv, (j0 + 18) & 63);
                half4_t v0 = ((const half4_t*)(zin + (size_t)c0 * OUT_F))[ql];
                half4_t v1 = ((const half4_t*)(zin + (size_t)c1 * OUT_F))[ql];
                half4_t v2 = ((const half4_t*)(zin + (size_t)c2 * OUT_F))[ql];
                half4_t v3 = ((const half4_t*)(zin + (size_t)c3 * OUT_F))[ql];
                float m0 = (j0      < lim) ? 1.f : 0.f;
                float m1 = (j0 +  6 < lim) ? 1.f : 0.f;
                float m2 = (j0 + 12 < lim) ? 1.f : 0.f;
                float m3 = (j0 + 18 < lim) ? 1.f : 0.f;
                acc.x += m0 * (float)v0.x; acc.y += m0 * (float)v0.y;
                acc.z += m0 * (float)v0.z; acc.w += m0 * (float)v0.w;
                acc.x += m1 * (float)v1.x; acc.y += m1 * (float)v1.y;
                acc.z += m1 * (float)v1.z; acc.w += m1 * (float)v1.w;
                acc.x += m2 * (float)v2.x; acc.y += m2 * (float)v2.y;
                acc.z += m2 * (float)v2.z; acc.w += m2 * (float)v2.w;
                acc.x += m3 * (float)v3.x; acc.y += m3 * (float)v3.y;
                acc.z += m3 * (float)v3.z; acc.w += m3 * (float)v3.w;
            }
        }
        // reduce 6 slots: fold +30, then +10 and +20
        float4 t1;
        t1.x = __shfl(acc.x, (lane + 30) & 63); t1.y = __shfl(acc.y, (lane + 30) & 63);
        t1.z = __shfl(acc.z, (lane + 30) & 63); t1.w = __shfl(acc.w, (lane + 30) & 63);
        if (lane < 30) { acc.x += t1.x; acc.y += t1.y; acc.z += t1.z; acc.w += t1.w; }
        float4 t2, t3;
        t2.x = __shfl(acc.x, (lane + 10) & 63); t2.y = __shfl(acc.y, (lane + 10) & 63);
        t2.z = __shfl(acc.z, (lane + 10) & 63); t2.w = __shfl(acc.w, (lane + 10) & 63);
        t3.x = __shfl(acc.x, (lane + 20) & 63); t3.y = __shfl(acc.y, (lane + 20) & 63);
        t3.z = __shfl(acc.z, (lane + 20) & 63); t3.w = __shfl(acc.w, (lane + 20) & 63);
        if (lane < 10) {
            acc.x += t2.x + t3.x; acc.y += t2.y + t3.y;
            acc.z += t2.z + t3.z; acc.w += t2.w + t3.w;
            float d = dinv[node];
            if (FINAL) {
                float* p = xc + cl[node] * OUT_F + ql * 4;
                atomicAdd(p + 0, acc.x * d); atomicAdd(p + 1, acc.y * d);
                atomicAdd(p + 2, acc.z * d); atomicAdd(p + 3, acc.w * d);
            } else {
                float s = d * d;
                half4_t o;
                o.x = (half_t)(acc.x * s); o.y = (half_t)(acc.y * s);
                o.z = (half_t)(acc.z * s); o.w = (half_t)(acc.w * s);
                srow[((w << 2) + i) * 10 + ql] = o;
            }
        }
    }
    if (!FINAL) {
        __syncthreads();
        if (t < 160) ((half4_t*)zout)[(size_t)blockIdx.x * 160 + t] = srow[t];
    }
}

// ---------------------------------------------------------------- epilogue: out[n] = xc[cl[n]]/cnt + b
__global__ void epilogue_kernel(const float4* __restrict__ xc4, const int* __restrict__ ccnt,
                                const float4* __restrict__ b4, const int* __restrict__ cl,
                                float4* __restrict__ out4) {
    int i = blockIdx.x * 256 + threadIdx.x;
    if (i >= N_NODES * (OUT_F / 4)) return;
    int node = i / 10;
    int q = i - node * 10;
    int c = cl[node];
    float inv = 1.0f / fmaxf((float)ccnt[c], 1.0f);
    float4 v = xc4[c * 10 + q];
    float4 bb = b4[q];
    v.x = v.x * inv + bb.x; v.y = v.y * inv + bb.y;
    v.z = v.z * inv + bb.z; v.w = v.w * inv + bb.w;
    out4[i] = v;
}

// ---------------------------------------------------------------- launch
extern "C" void kernel_launch(void* const* d_in, const int* in_sizes, int n_in,
                              void* d_out, int out_size, void* d_ws, size_t ws_size,
                              hipStream_t stream) {
    const float* x    = (const float*)d_in[0];
    const int*   rows = (const int*)d_in[1];
    const int*   cols = (const int*)d_in[1] + N_EDGES;
    const int*   cl   = (const int*)d_in[2];
    const float* W    = (const float*)d_in[4];
    const float* b    = (const float*)d_in[5];
    float* out = (float*)d_out;

    size_t off = 0;
    auto alloc = [&](size_t elems) -> void* {          // 256 B aligned
        void* p = (char*)d_ws + off * 4;
        off += (elems + 63) & ~(size_t)63;
        return p;
    };
    // zeroed region first (single memset): ccnt | xc_sum | bcursor
    int*   ccnt    = (int*)alloc(N_CLUSTERS);
    float* xc_sum  = (float*)alloc((size_t)N_CLUSTERS * OUT_F);
    int*   bcursor = (int*)alloc(NBUCK);
    size_t zero_elems = off;
    float* dinv      = (float*)alloc(N_NODES);
    uint2* rowinfo   = (uint2*)alloc((size_t)N_NODES * 2);
    int*   csr_col   = (int*)alloc((size_t)NBUCK * CAP);             // 8 MB
    unsigned* bins   = (unsigned*)alloc((size_t)NBUCK * CAP);        // 8 MB
    half_t* bufA     = (half_t*)alloc((size_t)N_NODES * OUT_F / 2);  // 8 MB fp16
    half_t* bufB     = (half_t*)alloc((size_t)N_NODES * OUT_F / 2);  // 8 MB fp16
    (void)ws_size; (void)in_sizes; (void)n_in; (void)out_size;

    hipMemsetAsync(d_ws, 0, zero_elems * 4, stream);

    const int TB = (N_EDGES + TILE_E - 1) / TILE_E;   // 391
    const int HB = N_NODES / 16;                      // 6250

    bin_scatter_kernel<<<TB, 256, 0, stream>>>(rows, cols, bcursor, bins);
    csr_build_kernel<<<NBUCK, 256, 0, stream>>>(bins, bcursor, csr_col, rowinfo,
                                                dinv, cl, ccnt);

    prologue_kernel<<<(2 * N_NODES + 255) / 256, 256, 0, stream>>>(
        (const float4*)x, W, dinv, bufA);

    hop40_kernel<0><<<HB, 256, 0, stream>>>(bufA, bufB, rowinfo, csr_col, dinv, cl, xc_sum);
    hop40_kernel<0><<<HB, 256, 0, stream>>>(bufB, bufA, rowinfo, csr_col, dinv, cl, xc_sum);
    hop40_kernel<1><<<HB, 256, 0, stream>>>(bufA, (half_t*)nullptr, rowinfo, csr_col, dinv, cl, xc_sum);

    epilogue_kernel<<<(N_NODES * (OUT_F / 4) + 255) / 256, 256, 0, stream>>>(
        (const float4*)xc_sum, ccnt, (const float4*)b, cl, (float4*)out);
}